// Round 1
// baseline (123.780 us; speedup 1.0000x reference)
//
#include <hip/hip_runtime.h>

// QRNN fo-pool: B=8, C=256, H=256, T=4096, K=2
// Pipeline: P1 (x -> xbT bf16 [B][T][C]), P2 (Wz/Wf/Wo -> Wcat bf16 [3H][2C]),
// G (MFMA GEMM -> z,f,o fp32 [3][B][H][T] in ws, with bias+activation fused),
// S1 (chunked local scan, chunk=32: c_local -> out.c, cumprod(f) -> out.h, aggregates),
// S2 (scan over chunk aggregates -> carry_in), S3 (fixup c += cumprod*carry; h = o*c).

typedef unsigned short ushort_t;
typedef __attribute__((ext_vector_type(8))) short short8_t;
typedef __attribute__((ext_vector_type(4))) float f32x4;

#define B_ 8
#define C_ 256
#define H_ 256
#define T_ 4096
#define TCH 32          // scan chunk length
#define NCH 128         // T_/TCH

__device__ __forceinline__ unsigned short f2bf(float f) {
  unsigned int u = __float_as_uint(f);
  u += 0x7fffu + ((u >> 16) & 1u);   // RNE
  return (unsigned short)(u >> 16);
}
__device__ __forceinline__ float sigm(float v) { return 1.f / (1.f + __expf(-v)); }
__device__ __forceinline__ float tanh_f(float v) { return 2.f / (1.f + __expf(-2.f * v)) - 1.f; }

// ---------------- P1: transpose+convert x [B][C][T] f32 -> xbT [B][T][C] bf16 ----------
__global__ __launch_bounds__(256) void qrnn_p1(const float* __restrict__ x,
                                               ushort_t* __restrict__ xbT) {
  __shared__ float tile[32][33];
  const int tx = threadIdx.x, ty = threadIdx.y;      // (32,8)
  const int b = blockIdx.z, c0 = blockIdx.y * 32, t0 = blockIdx.x * 32;
#pragma unroll
  for (int p = 0; p < 4; ++p) {
    const int c = ty + p * 8;
    tile[c][tx] = x[((size_t)(b * C_ + c0 + c)) * T_ + t0 + tx];
  }
  __syncthreads();
#pragma unroll
  for (int p = 0; p < 4; ++p) {
    const int tt = ty + p * 8;
    xbT[((size_t)b * T_ + t0 + tt) * C_ + c0 + tx] = f2bf(tile[tx][tt]);
  }
}

// ---------------- P2: Wcat[g][h][k'] bf16; k'<256 -> W[h][k'][1] (x_t), else W[h][k'-256][0] (x_{t-1})
__global__ __launch_bounds__(256) void qrnn_p2(const float* __restrict__ Wz,
                                               const float* __restrict__ Wf,
                                               const float* __restrict__ Wo,
                                               ushort_t* __restrict__ wc) {
  const int idx = blockIdx.x * 256 + threadIdx.x;    // < 3*256*512
  const int g = idx >> 17;
  const int rem = idx & 131071;
  const int h = rem >> 9;
  const int kp = rem & 511;
  const int c = kp & 255;
  const int tap = (kp < 256) ? 1 : 0;
  const float* W = (g == 0) ? Wz : ((g == 1) ? Wf : Wo);
  wc[idx] = f2bf(W[((size_t)h * C_ + c) * 2 + tap]);
}

// ---------------- G: bf16 MFMA GEMM [768 x 512] x [512 x T] per batch + bias + act ------
__global__ __launch_bounds__(256) void qrnn_gates(const ushort_t* __restrict__ xbT,
                                                  const ushort_t* __restrict__ wc,
                                                  const float* __restrict__ bz,
                                                  const float* __restrict__ bfv,
                                                  const float* __restrict__ bo,
                                                  float* __restrict__ zfo) {
  __shared__ ushort_t As[128][40];   // [m][k] pad->40 (16B-aligned rows, spreads banks)
  __shared__ ushort_t Bs[128][40];   // [t][k]
  const int tid = threadIdx.x;
  const int lane = tid & 63;
  const int wid = tid >> 6;
  const int wm = wid >> 1, wn = wid & 1;
  const int l15 = lane & 15, g4 = lane >> 4;
  const int b = blockIdx.z;
  const int m0 = blockIdx.y * 128;   // row in stacked [z|f|o] = [0,768)
  const int t0 = blockIdx.x * 128;

  const int r = tid >> 1;            // staging row 0..127
  const int ko = (tid & 1) * 16;     // staging k-offset 0 or 16

  f32x4 acc[4][4];
#pragma unroll
  for (int i = 0; i < 4; ++i)
#pragma unroll
    for (int j = 0; j < 4; ++j) acc[i][j] = (f32x4){0.f, 0.f, 0.f, 0.f};

  for (int ks = 0; ks < 16; ++ks) {
    const int kk = ks * 32;
    {  // A stage: Wcat rows
      const uint4* src = reinterpret_cast<const uint4*>(wc + (size_t)(m0 + r) * 512 + kk + ko);
      uint4 v0 = src[0], v1 = src[1];
      *reinterpret_cast<uint4*>(&As[r][ko]) = v0;
      *reinterpret_cast<uint4*>(&As[r][ko + 8]) = v1;
    }
    {  // B stage: x rows (k<256 -> x[t], k>=256 -> x[t-1])
      const int half = ks >> 3;
      const int cb = kk - half * 256;
      const int trow = t0 + r - half;
      uint4 v0 = make_uint4(0, 0, 0, 0), v1 = make_uint4(0, 0, 0, 0);
      if (trow >= 0) {
        const uint4* src =
            reinterpret_cast<const uint4*>(xbT + ((size_t)(b * T_ + trow)) * C_ + cb + ko);
        v0 = src[0];
        v1 = src[1];
      }
      *reinterpret_cast<uint4*>(&Bs[r][ko]) = v0;
      *reinterpret_cast<uint4*>(&Bs[r][ko + 8]) = v1;
    }
    __syncthreads();
    short8_t a[4], bb[4];
#pragma unroll
    for (int mi = 0; mi < 4; ++mi)
      a[mi] = *reinterpret_cast<const short8_t*>(&As[wm * 64 + mi * 16 + l15][g4 * 8]);
#pragma unroll
    for (int ni = 0; ni < 4; ++ni)
      bb[ni] = *reinterpret_cast<const short8_t*>(&Bs[wn * 64 + ni * 16 + l15][g4 * 8]);
#pragma unroll
    for (int mi = 0; mi < 4; ++mi)
#pragma unroll
      for (int ni = 0; ni < 4; ++ni)
        acc[mi][ni] = __builtin_amdgcn_mfma_f32_16x16x32_bf16(a[mi], bb[ni], acc[mi][ni], 0, 0, 0);
    __syncthreads();
  }

  // epilogue: bias + activation, store fp32 to zfo[gate][b][h][t]
  const int gate = m0 >> 8;          // M-tile is entirely inside one gate
  const float* bias = (gate == 0) ? bz : ((gate == 1) ? bfv : bo);
  const int hb = (m0 & 255) + wm * 64;
  float* obase = zfo + ((size_t)(gate * B_ + b)) * H_ * T_;
#pragma unroll
  for (int mi = 0; mi < 4; ++mi) {
#pragma unroll
    for (int r4 = 0; r4 < 4; ++r4) {
      const int h = hb + mi * 16 + g4 * 4 + r4;   // verified C/D map: row=(lane>>4)*4+reg
      const float bvv = bias[h];
      float* rowp = obase + (size_t)h * T_ + t0 + wn * 64 + l15;  // col=lane&15
#pragma unroll
      for (int ni = 0; ni < 4; ++ni) {
        float v = acc[mi][ni][r4] + bvv;
        v = (gate == 0) ? tanh_f(v) : sigm(v);
        rowp[ni * 16] = v;
      }
    }
  }
}

// ---------------- S1: per-chunk local scan (c_local, cumprod f) --------------------------
__global__ __launch_bounds__(256) void qrnn_s1(const float* __restrict__ zfo,
                                               float* __restrict__ outc,
                                               float* __restrict__ outcp,
                                               float* __restrict__ aggP,
                                               float* __restrict__ aggC) {
  __shared__ float lf[256][33];
  __shared__ float lz[256][33];
  const int tid = threadIdx.x;
  const int chunk = blockIdx.x;
  const int b = blockIdx.y;
  const int t0 = chunk * TCH;
  const float* zbase = zfo + (size_t)b * H_ * T_;
  const float* fbase = zfo + (size_t)(B_ + b) * H_ * T_;
  const int lr = tid >> 3, lc = (tid & 7) * 4;
#pragma unroll
  for (int pass = 0; pass < 8; ++pass) {
    const int row = pass * 32 + lr;
    float4 fv = *reinterpret_cast<const float4*>(fbase + (size_t)row * T_ + t0 + lc);
    float4 zv = *reinterpret_cast<const float4*>(zbase + (size_t)row * T_ + t0 + lc);
    lf[row][lc] = fv.x; lf[row][lc + 1] = fv.y; lf[row][lc + 2] = fv.z; lf[row][lc + 3] = fv.w;
    lz[row][lc] = zv.x; lz[row][lc + 1] = zv.y; lz[row][lc + 2] = zv.z; lz[row][lc + 3] = zv.w;
  }
  __syncthreads();
  float c = 0.f, p = 1.f;
#pragma unroll
  for (int t = 0; t < TCH; ++t) {
    const float f = lf[tid][t], z = lz[tid][t];
    c = f * (c - z) + z;   // = f*c + (1-f)*z
    p *= f;
    lf[tid][t] = p;
    lz[tid][t] = c;
  }
  __syncthreads();
  float* cbase = outc + (size_t)b * H_ * T_;
  float* pbase = outcp + (size_t)b * H_ * T_;
#pragma unroll
  for (int pass = 0; pass < 8; ++pass) {
    const int row = pass * 32 + lr;
    float4 cv = make_float4(lz[row][lc], lz[row][lc + 1], lz[row][lc + 2], lz[row][lc + 3]);
    float4 pv = make_float4(lf[row][lc], lf[row][lc + 1], lf[row][lc + 2], lf[row][lc + 3]);
    *reinterpret_cast<float4*>(cbase + (size_t)row * T_ + t0 + lc) = cv;
    *reinterpret_cast<float4*>(pbase + (size_t)row * T_ + t0 + lc) = pv;
  }
  aggP[((size_t)b * NCH + chunk) * H_ + tid] = p;
  aggC[((size_t)b * NCH + chunk) * H_ + tid] = c;
}

// ---------------- S2: scan over chunk aggregates -> carry_in -----------------------------
__global__ __launch_bounds__(256) void qrnn_s2(const float* __restrict__ aggP,
                                               const float* __restrict__ aggC,
                                               float* __restrict__ cin) {
  const int b = blockIdx.x, h = threadIdx.x;
  float carry = 0.f;
  for (int jb = 0; jb < NCH; jb += 8) {
    float P[8], Cv[8];
#pragma unroll
    for (int u = 0; u < 8; ++u) {
      P[u] = aggP[((size_t)b * NCH + jb + u) * H_ + h];
      Cv[u] = aggC[((size_t)b * NCH + jb + u) * H_ + h];
    }
#pragma unroll
    for (int u = 0; u < 8; ++u) {
      cin[((size_t)b * NCH + jb + u) * H_ + h] = carry;
      carry = Cv[u] + P[u] * carry;
    }
  }
}

// ---------------- S3: fixup + h = o*c ----------------------------------------------------
__global__ __launch_bounds__(256) void qrnn_s3(float* __restrict__ outc,
                                               float* __restrict__ outh,
                                               const float* __restrict__ ows,
                                               const float* __restrict__ cin) {
  const int i4 = blockIdx.x * 256 + threadIdx.x;   // float4 index over B*H*T/4
  const int idx = i4 << 2;
  const int t = idx & (T_ - 1);
  const int bh = idx >> 12;
  const int chunk = t >> 5;
  const float carry = cin[((size_t)(bh >> 8) * NCH + chunk) * H_ + (bh & 255)];
  float4 cl = reinterpret_cast<const float4*>(outc)[i4];
  float4 cp = reinterpret_cast<const float4*>(outh)[i4];
  float4 ov = reinterpret_cast<const float4*>(ows)[i4];
  float4 cf = make_float4(cl.x + cp.x * carry, cl.y + cp.y * carry, cl.z + cp.z * carry,
                          cl.w + cp.w * carry);
  float4 hv = make_float4(ov.x * cf.x, ov.y * cf.y, ov.z * cf.z, ov.w * cf.w);
  reinterpret_cast<float4*>(outc)[i4] = cf;
  reinterpret_cast<float4*>(outh)[i4] = hv;
}

extern "C" void kernel_launch(void* const* d_in, const int* in_sizes, int n_in,
                              void* d_out, int out_size, void* d_ws, size_t ws_size,
                              hipStream_t stream) {
  const float* x  = (const float*)d_in[0];
  const float* Wz = (const float*)d_in[1];
  const float* bz = (const float*)d_in[2];
  const float* Wf = (const float*)d_in[3];
  const float* bfv= (const float*)d_in[4];
  const float* Wo = (const float*)d_in[5];
  const float* bo = (const float*)d_in[6];
  // Wi/bi (d_in[7], d_in[8]) are dead in the reference.

  float* outh = (float*)d_out;                        // [B][H][T]
  float* outc = outh + (size_t)B_ * H_ * T_;          // [B][H][T]

  // workspace layout (bytes)
  constexpr size_t XBT_OFF = 0;                       // 16,777,216
  constexpr size_t WC_OFF  = 16777216;                //    786,432
  constexpr size_t ZFO_OFF = 17563648;                // 100,663,296
  constexpr size_t AGP_OFF = 118226944;               //  1,048,576
  constexpr size_t AGC_OFF = 119275520;               //  1,048,576
  constexpr size_t CIN_OFF = 120324096;               //  1,048,576
  constexpr size_t WS_NEED = 121372672;
  if (ws_size < WS_NEED) return;

  ushort_t* xbT = (ushort_t*)((char*)d_ws + XBT_OFF);
  ushort_t* wcp = (ushort_t*)((char*)d_ws + WC_OFF);
  float* zfo  = (float*)((char*)d_ws + ZFO_OFF);
  float* aggP = (float*)((char*)d_ws + AGP_OFF);
  float* aggC = (float*)((char*)d_ws + AGC_OFF);
  float* cin  = (float*)((char*)d_ws + CIN_OFF);

  qrnn_p1<<<dim3(T_ / 32, C_ / 32, B_), dim3(32, 8), 0, stream>>>(x, xbT);
  qrnn_p2<<<dim3((3 * H_ * 512) / 256), 256, 0, stream>>>(Wz, Wf, Wo, wcp);
  qrnn_gates<<<dim3(T_ / 128, 6, B_), 256, 0, stream>>>(xbT, wcp, bz, bfv, bo, zfo);
  qrnn_s1<<<dim3(NCH, B_), 256, 0, stream>>>(zfo, outc, outh, aggP, aggC);
  qrnn_s2<<<dim3(B_), 256, 0, stream>>>(aggP, aggC, cin);
  qrnn_s3<<<dim3((B_ * H_ * T_ / 4) / 256), 256, 0, stream>>>(outc, outh,
      zfo + (size_t)2 * B_ * H_ * T_, cin);
}

// Round 2
// 121.344 us; speedup vs baseline: 1.0201x; 1.0201x over previous
//
#include <hip/hip_runtime.h>

// QRNN fo-pool: B=8, C=256, H=256, T=4096, K=2
// P0 (zero pad row), P1 (x -> xp bf16 [B][T+1][C], row t+1 = x_t, row 0 = 0),
// P2 (Wz/Wf/Wo -> Wcat bf16 [3H][2C]),
// G (MFMA GEMM via global_load_lds + XOR-swizzled LDS -> z,f,o fp32, bias+act fused),
// S1 (chunk=32 local scan), S2 (aggregate scan), S3 (fixup + h = o*c).

typedef unsigned short ushort_t;
typedef __attribute__((ext_vector_type(8))) short short8_t;
typedef __attribute__((ext_vector_type(4))) float f32x4;

#define B_ 8
#define C_ 256
#define H_ 256
#define T_ 4096
#define TCH 32          // scan chunk length
#define NCH 128         // T_/TCH

__device__ __forceinline__ unsigned short f2bf(float f) {
  unsigned int u = __float_as_uint(f);
  u += 0x7fffu + ((u >> 16) & 1u);   // RNE
  return (unsigned short)(u >> 16);
}
__device__ __forceinline__ float sigm(float v) { return 1.f / (1.f + __expf(-v)); }
__device__ __forceinline__ float tanh_f(float v) { return 2.f / (1.f + __expf(-2.f * v)) - 1.f; }

__device__ __forceinline__ void gl16(const ushort_t* g, ushort_t* l) {
  __builtin_amdgcn_global_load_lds(
      (const __attribute__((address_space(1))) unsigned int*)g,
      (__attribute__((address_space(3))) unsigned int*)l, 16, 0, 0);
}

// ---------------- P0: zero the pad row (t = -1) for each batch ---------------------------
__global__ void qrnn_pad(ushort_t* __restrict__ xp) {
  const int tid = threadIdx.x;
#pragma unroll
  for (int b = 0; b < B_; ++b) xp[((size_t)b * (T_ + 1)) * C_ + tid] = 0;
}

// ---------------- P1: transpose+convert x [B][C][T] f32 -> xp [B][T+1][C] bf16 ----------
__global__ __launch_bounds__(256) void qrnn_p1(const float* __restrict__ x,
                                               ushort_t* __restrict__ xp) {
  __shared__ float tile[32][129];
  const int tid = threadIdx.x;
  const int b = blockIdx.z, c0 = blockIdx.y * 32, t0 = blockIdx.x * 128;
#pragma unroll
  for (int p = 0; p < 4; ++p) {
    const int j = tid + p * 256;        // 0..1023 float4 chunks
    const int c = j >> 5, q = j & 31;
    float4 v = *reinterpret_cast<const float4*>(x + ((size_t)(b * C_ + c0 + c)) * T_ + t0 + q * 4);
    tile[c][q * 4 + 0] = v.x; tile[c][q * 4 + 1] = v.y;
    tile[c][q * 4 + 2] = v.z; tile[c][q * 4 + 3] = v.w;
  }
  __syncthreads();
  const int t = tid >> 1, ch = (tid & 1) * 16;
  ushort_t o[16];
#pragma unroll
  for (int i = 0; i < 16; ++i) o[i] = f2bf(tile[ch + i][t]);
  ushort_t* dst = xp + ((size_t)b * (T_ + 1) + 1 + t0 + t) * C_ + c0 + ch;
  *reinterpret_cast<uint4*>(dst) = *reinterpret_cast<uint4*>(&o[0]);
  *reinterpret_cast<uint4*>(dst + 8) = *reinterpret_cast<uint4*>(&o[8]);
}

// ---------------- P2: Wcat[g][h][k'] bf16; k'<256 -> W[h][k'][1] (x_t), else W[h][k'-256][0]
__global__ __launch_bounds__(256) void qrnn_p2(const float* __restrict__ Wz,
                                               const float* __restrict__ Wf,
                                               const float* __restrict__ Wo,
                                               ushort_t* __restrict__ wc) {
  const int idx = blockIdx.x * 256 + threadIdx.x;    // < 3*256*512
  const int g = idx >> 17;
  const int rem = idx & 131071;
  const int h = rem >> 9;
  const int kp = rem & 511;
  const int c = kp & 255;
  const int tap = (kp < 256) ? 1 : 0;
  const float* W = (g == 0) ? Wz : ((g == 1) ? Wf : Wo);
  wc[idx] = f2bf(W[((size_t)h * C_ + c) * 2 + tap]);
}

// ---------------- G: bf16 MFMA GEMM [768 x 512] x [512 x T] per batch + bias + act ------
// m97 structure: global_load_lds(16B) staging, linear LDS dest, pre-swizzled global source
// (chunk s ^= (row>>1)&3), swizzled ds_read_b128. 2 barriers / K-step.
__global__ __launch_bounds__(256) void qrnn_gates(const ushort_t* __restrict__ xp,
                                                  const ushort_t* __restrict__ wc,
                                                  const float* __restrict__ bz,
                                                  const float* __restrict__ bfv,
                                                  const float* __restrict__ bo,
                                                  float* __restrict__ zfo) {
  __shared__ ushort_t As[128 * 32];   // [row][32k] linear, 8KB
  __shared__ ushort_t Bs[128 * 32];
  const int tid = threadIdx.x;
  const int lane = tid & 63;
  const int wid = tid >> 6;
  const int wm = wid >> 1, wn = wid & 1;
  const int l15 = lane & 15, g4 = lane >> 4;
  const int b = blockIdx.z;
  const int m0 = blockIdx.y * 128;   // row in stacked [z|f|o]
  const int t0 = blockIdx.x * 128;

  // staging: 512 chunks of 16B per tile; chunk j -> row=j>>2, slot=j&3; source slot XOR'd
  const int j0 = wid * 128 + lane;
  const int j1 = j0 + 64;
  const int r0 = j0 >> 2, s0 = (j0 & 3) ^ ((r0 >> 1) & 3);
  const int r1 = j1 >> 2, s1 = (j1 & 3) ^ ((r1 >> 1) & 3);
  const ushort_t* asrc0 = wc + (size_t)(m0 + r0) * 512 + s0 * 8;
  const ushort_t* asrc1 = wc + (size_t)(m0 + r1) * 512 + s1 * 8;
  const ushort_t* bsrc0 = xp + ((size_t)b * (T_ + 1) + t0 + r0) * C_ + s0 * 8;
  const ushort_t* bsrc1 = xp + ((size_t)b * (T_ + 1) + t0 + r1) * C_ + s1 * 8;
  ushort_t* AsD0 = As + (size_t)(wid * 128) * 8;        // wave-uniform dest bases
  ushort_t* AsD1 = As + (size_t)(wid * 128 + 64) * 8;
  ushort_t* BsD0 = Bs + (size_t)(wid * 128) * 8;
  ushort_t* BsD1 = Bs + (size_t)(wid * 128 + 64) * 8;

  f32x4 acc[4][4];
#pragma unroll
  for (int i = 0; i < 4; ++i)
#pragma unroll
    for (int j = 0; j < 4; ++j) acc[i][j] = (f32x4){0.f, 0.f, 0.f, 0.f};

  const int swz = (l15 >> 1) & 3;
  const int aslot = (g4 ^ swz) * 8;

  for (int ks = 0; ks < 16; ++ks) {
    const int ak = ks * 32;
    // B k-offset: k'<256 half reads x_t (padded row t+1 -> +C_), k'>=256 reads x_{t-1}
    const int bk = (ks >= 8) ? (ak - 256) : (C_ + ak);
    gl16(asrc0 + ak, AsD0);
    gl16(asrc1 + ak, AsD1);
    gl16(bsrc0 + bk, BsD0);
    gl16(bsrc1 + bk, BsD1);
    __syncthreads();
    short8_t a[4], bb[4];
#pragma unroll
    for (int mi = 0; mi < 4; ++mi) {
      const int row = wm * 64 + mi * 16 + l15;
      a[mi] = *reinterpret_cast<const short8_t*>(&As[row * 32 + aslot]);
    }
#pragma unroll
    for (int ni = 0; ni < 4; ++ni) {
      const int row = wn * 64 + ni * 16 + l15;
      bb[ni] = *reinterpret_cast<const short8_t*>(&Bs[row * 32 + aslot]);
    }
#pragma unroll
    for (int mi = 0; mi < 4; ++mi)
#pragma unroll
      for (int ni = 0; ni < 4; ++ni)
        acc[mi][ni] = __builtin_amdgcn_mfma_f32_16x16x32_bf16(a[mi], bb[ni], acc[mi][ni], 0, 0, 0);
    __syncthreads();
  }

  // epilogue: bias + activation, store fp32 to zfo[gate][b][h][t]
  const int gate = m0 >> 8;
  const float* bias = (gate == 0) ? bz : ((gate == 1) ? bfv : bo);
  const int hb = (m0 & 255) + wm * 64;
  float* obase = zfo + ((size_t)(gate * B_ + b)) * H_ * T_;
#pragma unroll
  for (int mi = 0; mi < 4; ++mi) {
#pragma unroll
    for (int r4 = 0; r4 < 4; ++r4) {
      const int h = hb + mi * 16 + g4 * 4 + r4;   // C/D map: row=(lane>>4)*4+reg
      const float bvv = bias[h];
      float* rowp = obase + (size_t)h * T_ + t0 + wn * 64 + l15;  // col=lane&15
#pragma unroll
      for (int ni = 0; ni < 4; ++ni) {
        float v = acc[mi][ni][r4] + bvv;
        v = (gate == 0) ? tanh_f(v) : sigm(v);
        rowp[ni * 16] = v;
      }
    }
  }
}

// ---------------- S1: per-chunk local scan (c_local, cumprod f) --------------------------
__global__ __launch_bounds__(256) void qrnn_s1(const float* __restrict__ zfo,
                                               float* __restrict__ outc,
                                               float* __restrict__ outcp,
                                               float* __restrict__ aggP,
                                               float* __restrict__ aggC) {
  __shared__ float lf[256][33];
  __shared__ float lz[256][33];
  const int tid = threadIdx.x;
  const int chunk = blockIdx.x;
  const int b = blockIdx.y;
  const int t0 = chunk * TCH;
  const float* zbase = zfo + (size_t)b * H_ * T_;
  const float* fbase = zfo + (size_t)(B_ + b) * H_ * T_;
  const int lr = tid >> 3, lc = (tid & 7) * 4;
#pragma unroll
  for (int pass = 0; pass < 8; ++pass) {
    const int row = pass * 32 + lr;
    float4 fv = *reinterpret_cast<const float4*>(fbase + (size_t)row * T_ + t0 + lc);
    float4 zv = *reinterpret_cast<const float4*>(zbase + (size_t)row * T_ + t0 + lc);
    lf[row][lc] = fv.x; lf[row][lc + 1] = fv.y; lf[row][lc + 2] = fv.z; lf[row][lc + 3] = fv.w;
    lz[row][lc] = zv.x; lz[row][lc + 1] = zv.y; lz[row][lc + 2] = zv.z; lz[row][lc + 3] = zv.w;
  }
  __syncthreads();
  float c = 0.f, p = 1.f;
#pragma unroll
  for (int t = 0; t < TCH; ++t) {
    const float f = lf[tid][t], z = lz[tid][t];
    c = f * (c - z) + z;   // = f*c + (1-f)*z
    p *= f;
    lf[tid][t] = p;
    lz[tid][t] = c;
  }
  __syncthreads();
  float* cbase = outc + (size_t)b * H_ * T_;
  float* pbase = outcp + (size_t)b * H_ * T_;
#pragma unroll
  for (int pass = 0; pass < 8; ++pass) {
    const int row = pass * 32 + lr;
    float4 cv = make_float4(lz[row][lc], lz[row][lc + 1], lz[row][lc + 2], lz[row][lc + 3]);
    float4 pv = make_float4(lf[row][lc], lf[row][lc + 1], lf[row][lc + 2], lf[row][lc + 3]);
    *reinterpret_cast<float4*>(cbase + (size_t)row * T_ + t0 + lc) = cv;
    *reinterpret_cast<float4*>(pbase + (size_t)row * T_ + t0 + lc) = pv;
  }
  aggP[((size_t)b * NCH + chunk) * H_ + tid] = p;
  aggC[((size_t)b * NCH + chunk) * H_ + tid] = c;
}

// ---------------- S2: scan over chunk aggregates -> carry_in -----------------------------
__global__ __launch_bounds__(256) void qrnn_s2(const float* __restrict__ aggP,
                                               const float* __restrict__ aggC,
                                               float* __restrict__ cin) {
  const int b = blockIdx.x, h = threadIdx.x;
  float carry = 0.f;
  for (int jb = 0; jb < NCH; jb += 8) {
    float P[8], Cv[8];
#pragma unroll
    for (int u = 0; u < 8; ++u) {
      P[u] = aggP[((size_t)b * NCH + jb + u) * H_ + h];
      Cv[u] = aggC[((size_t)b * NCH + jb + u) * H_ + h];
    }
#pragma unroll
    for (int u = 0; u < 8; ++u) {
      cin[((size_t)b * NCH + jb + u) * H_ + h] = carry;
      carry = Cv[u] + P[u] * carry;
    }
  }
}

// ---------------- S3: fixup + h = o*c ----------------------------------------------------
__global__ __launch_bounds__(256) void qrnn_s3(float* __restrict__ outc,
                                               float* __restrict__ outh,
                                               const float* __restrict__ ows,
                                               const float* __restrict__ cin) {
  const int i4 = blockIdx.x * 256 + threadIdx.x;   // float4 index over B*H*T/4
  const int idx = i4 << 2;
  const int t = idx & (T_ - 1);
  const int bh = idx >> 12;
  const int chunk = t >> 5;
  const float carry = cin[((size_t)(bh >> 8) * NCH + chunk) * H_ + (bh & 255)];
  float4 cl = reinterpret_cast<const float4*>(outc)[i4];
  float4 cp = reinterpret_cast<const float4*>(outh)[i4];
  float4 ov = reinterpret_cast<const float4*>(ows)[i4];
  float4 cf = make_float4(cl.x + cp.x * carry, cl.y + cp.y * carry, cl.z + cp.z * carry,
                          cl.w + cp.w * carry);
  float4 hv = make_float4(ov.x * cf.x, ov.y * cf.y, ov.z * cf.z, ov.w * cf.w);
  reinterpret_cast<float4*>(outc)[i4] = cf;
  reinterpret_cast<float4*>(outh)[i4] = hv;
}

extern "C" void kernel_launch(void* const* d_in, const int* in_sizes, int n_in,
                              void* d_out, int out_size, void* d_ws, size_t ws_size,
                              hipStream_t stream) {
  const float* x  = (const float*)d_in[0];
  const float* Wz = (const float*)d_in[1];
  const float* bz = (const float*)d_in[2];
  const float* Wf = (const float*)d_in[3];
  const float* bfv= (const float*)d_in[4];
  const float* Wo = (const float*)d_in[5];
  const float* bo = (const float*)d_in[6];
  // Wi/bi (d_in[7], d_in[8]) are dead in the reference.

  float* outh = (float*)d_out;                        // [B][H][T]
  float* outc = outh + (size_t)B_ * H_ * T_;          // [B][H][T]

  // workspace layout (bytes)
  constexpr size_t XP_OFF  = 0;                       // B*(T+1)*C*2 = 16,781,312
  constexpr size_t WC_OFF  = 16781312;                //    786,432
  constexpr size_t ZFO_OFF = 17567744;                // 100,663,296
  constexpr size_t AGP_OFF = 118231040;               //  1,048,576
  constexpr size_t AGC_OFF = 119279616;               //  1,048,576
  constexpr size_t CIN_OFF = 120328192;               //  1,048,576
  constexpr size_t WS_NEED = 121376768;
  if (ws_size < WS_NEED) return;

  ushort_t* xp  = (ushort_t*)((char*)d_ws + XP_OFF);
  ushort_t* wcp = (ushort_t*)((char*)d_ws + WC_OFF);
  float* zfo  = (float*)((char*)d_ws + ZFO_OFF);
  float* aggP = (float*)((char*)d_ws + AGP_OFF);
  float* aggC = (float*)((char*)d_ws + AGC_OFF);
  float* cin  = (float*)((char*)d_ws + CIN_OFF);

  qrnn_pad<<<1, 256, 0, stream>>>(xp);
  qrnn_p1<<<dim3(T_ / 128, C_ / 32, B_), 256, 0, stream>>>(x, xp);
  qrnn_p2<<<dim3((3 * H_ * 512) / 256), 256, 0, stream>>>(Wz, Wf, Wo, wcp);
  qrnn_gates<<<dim3(T_ / 128, 6, B_), 256, 0, stream>>>(xp, wcp, bz, bfv, bo, zfo);
  qrnn_s1<<<dim3(NCH, B_), 256, 0, stream>>>(zfo, outc, outh, aggP, aggC);
  qrnn_s2<<<dim3(B_), 256, 0, stream>>>(aggP, aggC, cin);
  qrnn_s3<<<dim3((B_ * H_ * T_ / 4) / 256), 256, 0, stream>>>(outc, outh,
      zfo + (size_t)2 * B_ * H_ * T_, cin);
}

// Round 3
// 108.975 us; speedup vs baseline: 1.1359x; 1.1135x over previous
//
#include <hip/hip_runtime.h>

// QRNN fo-pool: B=8, C=256, H=256, T=4096, K=2
// P1 (x -> xp bf16 [B][T+1][C], row t+1 = x_t, row 0 = 0),
// P2 (Wz/Wf/Wo -> Wcat bf16 [3H][2C]; block 0 also zeroes xp pad rows),
// G (2-phase double-buffered MFMA GEMM via global_load_lds, bias+act fused),
// S1 (chunk=32 aggregates only), S2 (aggregate scan -> carry_in),
// S3 (local re-scan with carry folded; writes c and h=o*c).

typedef unsigned short ushort_t;
typedef __attribute__((ext_vector_type(8))) short short8_t;
typedef __attribute__((ext_vector_type(4))) float f32x4;

#define B_ 8
#define C_ 256
#define H_ 256
#define T_ 4096
#define TCH 32          // scan chunk length
#define NCH 128         // T_/TCH

__device__ __forceinline__ unsigned short f2bf(float f) {
  unsigned int u = __float_as_uint(f);
  u += 0x7fffu + ((u >> 16) & 1u);   // RNE
  return (unsigned short)(u >> 16);
}
__device__ __forceinline__ float sigm(float v) { return 1.f / (1.f + __expf(-v)); }
__device__ __forceinline__ float tanh_f(float v) { return 2.f / (1.f + __expf(-2.f * v)) - 1.f; }

__device__ __forceinline__ void gl16(const ushort_t* g, ushort_t* l) {
  __builtin_amdgcn_global_load_lds(
      (const __attribute__((address_space(1))) unsigned int*)g,
      (__attribute__((address_space(3))) unsigned int*)l, 16, 0, 0);
}

// ---------------- P1: transpose+convert x [B][C][T] f32 -> xp [B][T+1][C] bf16 ----------
__global__ __launch_bounds__(256) void qrnn_p1(const float* __restrict__ x,
                                               ushort_t* __restrict__ xp) {
  __shared__ float tile[32][129];
  const int tid = threadIdx.x;
  const int b = blockIdx.z, c0 = blockIdx.y * 32, t0 = blockIdx.x * 128;
#pragma unroll
  for (int p = 0; p < 4; ++p) {
    const int j = tid + p * 256;        // 0..1023 float4 chunks
    const int c = j >> 5, q = j & 31;
    float4 v = *reinterpret_cast<const float4*>(x + ((size_t)(b * C_ + c0 + c)) * T_ + t0 + q * 4);
    tile[c][q * 4 + 0] = v.x; tile[c][q * 4 + 1] = v.y;
    tile[c][q * 4 + 2] = v.z; tile[c][q * 4 + 3] = v.w;
  }
  __syncthreads();
  const int t = tid >> 1, ch = (tid & 1) * 16;
  ushort_t o[16];
#pragma unroll
  for (int i = 0; i < 16; ++i) o[i] = f2bf(tile[ch + i][t]);
  ushort_t* dst = xp + ((size_t)b * (T_ + 1) + 1 + t0 + t) * C_ + c0 + ch;
  *reinterpret_cast<uint4*>(dst) = *reinterpret_cast<uint4*>(&o[0]);
  *reinterpret_cast<uint4*>(dst + 8) = *reinterpret_cast<uint4*>(&o[8]);
}

// ---------------- P2: Wcat[g][h][k'] bf16; k'<256 -> W[h][k'][1] (x_t), else W[h][k'-256][0]
__global__ __launch_bounds__(256) void qrnn_p2(const float* __restrict__ Wz,
                                               const float* __restrict__ Wf,
                                               const float* __restrict__ Wo,
                                               ushort_t* __restrict__ wc,
                                               ushort_t* __restrict__ xp) {
  const int idx = blockIdx.x * 256 + threadIdx.x;    // < 3*256*512
  if (blockIdx.x == 0) {                             // zero pad rows (t = -1)
#pragma unroll
    for (int b = 0; b < B_; ++b) xp[((size_t)b * (T_ + 1)) * C_ + threadIdx.x] = 0;
  }
  const int g = idx >> 17;
  const int rem = idx & 131071;
  const int h = rem >> 9;
  const int kp = rem & 511;
  const int c = kp & 255;
  const int tap = (kp < 256) ? 1 : 0;
  const float* W = (g == 0) ? Wz : ((g == 1) ? Wf : Wo);
  wc[idx] = f2bf(W[((size_t)h * C_ + c) * 2 + tap]);
}

// ---------------- G: bf16 MFMA GEMM [768 x 512] x [512 x T] per batch + bias + act ------
// 2-phase double-buffered: stage K-step ks+1 into buf^1, compute buf, ONE barrier per step.
__global__ __launch_bounds__(256) void qrnn_gates(const ushort_t* __restrict__ xp,
                                                  const ushort_t* __restrict__ wc,
                                                  const float* __restrict__ bz,
                                                  const float* __restrict__ bfv,
                                                  const float* __restrict__ bo,
                                                  float* __restrict__ zfo) {
  __shared__ ushort_t As[2][128 * 32];   // 8KB each buf
  __shared__ ushort_t Bs[2][128 * 32];
  const int tid = threadIdx.x;
  const int lane = tid & 63;
  const int wid = tid >> 6;
  const int wm = wid >> 1, wn = wid & 1;
  const int l15 = lane & 15, g4 = lane >> 4;
  const int b = blockIdx.z;
  const int m0 = blockIdx.y * 128;   // row in stacked [z|f|o]
  const int t0 = blockIdx.x * 128;

  // staging: 512 chunks of 16B per tile; chunk j -> row=j>>2, slot=j&3; source slot XOR'd
  const int j0 = wid * 128 + lane;
  const int j1 = j0 + 64;
  const int r0 = j0 >> 2, s0 = (j0 & 3) ^ ((r0 >> 1) & 3);
  const int r1 = j1 >> 2, s1 = (j1 & 3) ^ ((r1 >> 1) & 3);
  const ushort_t* asrc0 = wc + (size_t)(m0 + r0) * 512 + s0 * 8;
  const ushort_t* asrc1 = wc + (size_t)(m0 + r1) * 512 + s1 * 8;
  const ushort_t* bsrc0 = xp + ((size_t)b * (T_ + 1) + t0 + r0) * C_ + s0 * 8;
  const ushort_t* bsrc1 = xp + ((size_t)b * (T_ + 1) + t0 + r1) * C_ + s1 * 8;
  const int dA0 = (wid * 128) * 8;       // wave-uniform dest element offsets
  const int dA1 = (wid * 128 + 64) * 8;

  f32x4 acc[4][4];
#pragma unroll
  for (int i = 0; i < 4; ++i)
#pragma unroll
    for (int j = 0; j < 4; ++j) acc[i][j] = (f32x4){0.f, 0.f, 0.f, 0.f};

  const int swz = (l15 >> 1) & 3;
  const int aslot = (g4 ^ swz) * 8;

  // prologue: stage ks=0 into buf 0
  {
    gl16(asrc0, &As[0][dA0]);
    gl16(asrc1, &As[0][dA1]);
    gl16(bsrc0 + C_, &Bs[0][dA0]);
    gl16(bsrc1 + C_, &Bs[0][dA1]);
  }
  __syncthreads();

#pragma unroll
  for (int ks = 0; ks < 16; ++ks) {
    const int cur = ks & 1;
    if (ks < 15) {
      const int nk = ks + 1;
      const int ak = nk * 32;
      const int bk = (nk >= 8) ? (ak - 256) : (C_ + ak);
      gl16(asrc0 + ak, &As[cur ^ 1][dA0]);
      gl16(asrc1 + ak, &As[cur ^ 1][dA1]);
      gl16(bsrc0 + bk, &Bs[cur ^ 1][dA0]);
      gl16(bsrc1 + bk, &Bs[cur ^ 1][dA1]);
    }
    short8_t a[4], bb[4];
#pragma unroll
    for (int mi = 0; mi < 4; ++mi) {
      const int row = wm * 64 + mi * 16 + l15;
      a[mi] = *reinterpret_cast<const short8_t*>(&As[cur][row * 32 + aslot]);
    }
#pragma unroll
    for (int ni = 0; ni < 4; ++ni) {
      const int row = wn * 64 + ni * 16 + l15;
      bb[ni] = *reinterpret_cast<const short8_t*>(&Bs[cur][row * 32 + aslot]);
    }
#pragma unroll
    for (int mi = 0; mi < 4; ++mi)
#pragma unroll
      for (int ni = 0; ni < 4; ++ni)
        acc[mi][ni] = __builtin_amdgcn_mfma_f32_16x16x32_bf16(a[mi], bb[ni], acc[mi][ni], 0, 0, 0);
    __syncthreads();   // drains this step's prefetch (vmcnt 0) + releases buf[cur]
  }

  // epilogue: bias + activation, store fp32 to zfo[gate][b][h][t]
  const int gate = m0 >> 8;
  const float* bias = (gate == 0) ? bz : ((gate == 1) ? bfv : bo);
  const int hb = (m0 & 255) + wm * 64;
  float* obase = zfo + ((size_t)(gate * B_ + b)) * H_ * T_;
#pragma unroll
  for (int mi = 0; mi < 4; ++mi) {
#pragma unroll
    for (int r4 = 0; r4 < 4; ++r4) {
      const int h = hb + mi * 16 + g4 * 4 + r4;   // C/D map: row=(lane>>4)*4+reg
      const float bvv = bias[h];
      float* rowp = obase + (size_t)h * T_ + t0 + wn * 64 + l15;  // col=lane&15
#pragma unroll
      for (int ni = 0; ni < 4; ++ni) {
        float v = acc[mi][ni][r4] + bvv;
        v = (gate == 0) ? tanh_f(v) : sigm(v);
        rowp[ni * 16] = v;
      }
    }
  }
}

// ---------------- S1: per-chunk aggregates only (P = cumprod f, C = local end value) ----
__global__ __launch_bounds__(256) void qrnn_s1(const float* __restrict__ zfo,
                                               float* __restrict__ aggP,
                                               float* __restrict__ aggC) {
  __shared__ float lf[256][33];
  __shared__ float lz[256][33];
  const int tid = threadIdx.x;
  const int chunk = blockIdx.x;
  const int b = blockIdx.y;
  const int t0 = chunk * TCH;
  const float* zbase = zfo + (size_t)b * H_ * T_;
  const float* fbase = zfo + (size_t)(B_ + b) * H_ * T_;
  const int lr = tid >> 3, lc = (tid & 7) * 4;
#pragma unroll
  for (int pass = 0; pass < 8; ++pass) {
    const int row = pass * 32 + lr;
    float4 fv = *reinterpret_cast<const float4*>(fbase + (size_t)row * T_ + t0 + lc);
    float4 zv = *reinterpret_cast<const float4*>(zbase + (size_t)row * T_ + t0 + lc);
    lf[row][lc] = fv.x; lf[row][lc + 1] = fv.y; lf[row][lc + 2] = fv.z; lf[row][lc + 3] = fv.w;
    lz[row][lc] = zv.x; lz[row][lc + 1] = zv.y; lz[row][lc + 2] = zv.z; lz[row][lc + 3] = zv.w;
  }
  __syncthreads();
  float c = 0.f, p = 1.f;
#pragma unroll
  for (int t = 0; t < TCH; ++t) {
    const float f = lf[tid][t], z = lz[tid][t];
    c = f * (c - z) + z;   // = f*c + (1-f)*z
    p *= f;
  }
  aggP[((size_t)b * NCH + chunk) * H_ + tid] = p;
  aggC[((size_t)b * NCH + chunk) * H_ + tid] = c;
}

// ---------------- S2: scan over chunk aggregates -> carry_in -----------------------------
__global__ __launch_bounds__(256) void qrnn_s2(const float* __restrict__ aggP,
                                               const float* __restrict__ aggC,
                                               float* __restrict__ cin) {
  const int b = blockIdx.x, h = threadIdx.x;
  float carry = 0.f;
  for (int jb = 0; jb < NCH; jb += 8) {
    float P[8], Cv[8];
#pragma unroll
    for (int u = 0; u < 8; ++u) {
      P[u] = aggP[((size_t)b * NCH + jb + u) * H_ + h];
      Cv[u] = aggC[((size_t)b * NCH + jb + u) * H_ + h];
    }
#pragma unroll
    for (int u = 0; u < 8; ++u) {
      cin[((size_t)b * NCH + jb + u) * H_ + h] = carry;
      carry = Cv[u] + P[u] * carry;
    }
  }
}

// ---------------- S3: local re-scan with carry folded; write c and h = o*c --------------
__global__ __launch_bounds__(256) void qrnn_s3(const float* __restrict__ zfo,
                                               const float* __restrict__ cin,
                                               float* __restrict__ outc,
                                               float* __restrict__ outh) {
  __shared__ float lz[128][33];
  __shared__ float lf[128][33];
  __shared__ float lo[128][33];
  const int tid = threadIdx.x;
  const int chunk = blockIdx.x;          // 0..127
  const int h0 = blockIdx.y * 128;       // 0 or 128
  const int b = blockIdx.z;
  const int t0 = chunk * TCH;
  const float* zb = zfo + (size_t)b * H_ * T_;
  const float* fb = zfo + (size_t)(B_ + b) * H_ * T_;
  const float* ob = zfo + (size_t)(2 * B_ + b) * H_ * T_;
#pragma unroll
  for (int i = 0; i < 4; ++i) {
    const int j = tid + i * 256;         // 0..1023
    const int row = j >> 3, c4 = (j & 7) * 4;
    const size_t goff = (size_t)(h0 + row) * T_ + t0 + c4;
    float4 zv = *reinterpret_cast<const float4*>(zb + goff);
    float4 fv = *reinterpret_cast<const float4*>(fb + goff);
    float4 ov = *reinterpret_cast<const float4*>(ob + goff);
    lz[row][c4] = zv.x; lz[row][c4 + 1] = zv.y; lz[row][c4 + 2] = zv.z; lz[row][c4 + 3] = zv.w;
    lf[row][c4] = fv.x; lf[row][c4 + 1] = fv.y; lf[row][c4 + 2] = fv.z; lf[row][c4 + 3] = fv.w;
    lo[row][c4] = ov.x; lo[row][c4 + 1] = ov.y; lo[row][c4 + 2] = ov.z; lo[row][c4 + 3] = ov.w;
  }
  __syncthreads();
  if (tid < 128) {
    float c = cin[((size_t)b * NCH + chunk) * H_ + h0 + tid];
#pragma unroll
    for (int t = 0; t < TCH; ++t) {
      const float f = lf[tid][t], z = lz[tid][t];
      c = f * (c - z) + z;
      lz[tid][t] = c;                 // c
      lf[tid][t] = lo[tid][t] * c;    // h = o*c (f slot reused)
    }
  }
  __syncthreads();
  float* cb = outc + (size_t)b * H_ * T_;
  float* hb = outh + (size_t)b * H_ * T_;
#pragma unroll
  for (int i = 0; i < 4; ++i) {
    const int j = tid + i * 256;
    const int row = j >> 3, c4 = (j & 7) * 4;
    const size_t goff = (size_t)(h0 + row) * T_ + t0 + c4;
    float4 cv = make_float4(lz[row][c4], lz[row][c4 + 1], lz[row][c4 + 2], lz[row][c4 + 3]);
    float4 hv = make_float4(lf[row][c4], lf[row][c4 + 1], lf[row][c4 + 2], lf[row][c4 + 3]);
    *reinterpret_cast<float4*>(cb + goff) = cv;
    *reinterpret_cast<float4*>(hb + goff) = hv;
  }
}

extern "C" void kernel_launch(void* const* d_in, const int* in_sizes, int n_in,
                              void* d_out, int out_size, void* d_ws, size_t ws_size,
                              hipStream_t stream) {
  const float* x  = (const float*)d_in[0];
  const float* Wz = (const float*)d_in[1];
  const float* bz = (const float*)d_in[2];
  const float* Wf = (const float*)d_in[3];
  const float* bfv= (const float*)d_in[4];
  const float* Wo = (const float*)d_in[5];
  const float* bo = (const float*)d_in[6];
  // Wi/bi (d_in[7], d_in[8]) are dead in the reference.

  float* outh = (float*)d_out;                        // [B][H][T]
  float* outc = outh + (size_t)B_ * H_ * T_;          // [B][H][T]

  // workspace layout (bytes)
  constexpr size_t XP_OFF  = 0;                       // B*(T+1)*C*2 = 16,781,312
  constexpr size_t WC_OFF  = 16781312;                //    786,432
  constexpr size_t ZFO_OFF = 17567744;                // 100,663,296
  constexpr size_t AGP_OFF = 118231040;               //  1,048,576
  constexpr size_t AGC_OFF = 119279616;               //  1,048,576
  constexpr size_t CIN_OFF = 120328192;               //  1,048,576
  constexpr size_t WS_NEED = 121376768;
  if (ws_size < WS_NEED) return;

  ushort_t* xp  = (ushort_t*)((char*)d_ws + XP_OFF);
  ushort_t* wcp = (ushort_t*)((char*)d_ws + WC_OFF);
  float* zfo  = (float*)((char*)d_ws + ZFO_OFF);
  float* aggP = (float*)((char*)d_ws + AGP_OFF);
  float* aggC = (float*)((char*)d_ws + AGC_OFF);
  float* cin  = (float*)((char*)d_ws + CIN_OFF);

  qrnn_p1<<<dim3(T_ / 128, C_ / 32, B_), 256, 0, stream>>>(x, xp);
  qrnn_p2<<<dim3((3 * H_ * 512) / 256), 256, 0, stream>>>(Wz, Wf, Wo, wcp, xp);
  qrnn_gates<<<dim3(T_ / 128, 6, B_), 256, 0, stream>>>(xp, wcp, bz, bfv, bo, zfo);
  qrnn_s1<<<dim3(NCH, B_), 256, 0, stream>>>(zfo, aggP, aggC);
  qrnn_s2<<<dim3(B_), 256, 0, stream>>>(aggP, aggC, cin);
  qrnn_s3<<<dim3(NCH, 2, B_), 256, 0, stream>>>(zfo, cin, outc, outh);
}

// Round 4
// 106.555 us; speedup vs baseline: 1.1617x; 1.0227x over previous
//
#include <hip/hip_runtime.h>

// QRNN fo-pool: B=8, C=256, H=256, T=4096, K=2
// P1 (x -> xp bf16 [B][T+1][C], row t+1 = x_t, row 0 = 0),
// P2 (Wz/Wf/Wo -> Wcat bf16 [3H][2C]; block 0 also zeroes xp pad rows),
// G (MFMA GEMM, counted-vmcnt depth-2 pipeline, raw s_barrier, bias+act fused),
// S1 (chunk=32 aggregates only), S2 (aggregate scan -> carry_in),
// S3 (local re-scan with carry folded; writes c and h=o*c).

typedef unsigned short ushort_t;
typedef __attribute__((ext_vector_type(8))) short short8_t;
typedef __attribute__((ext_vector_type(4))) float f32x4;

#define B_ 8
#define C_ 256
#define H_ 256
#define T_ 4096
#define TCH 32          // scan chunk length
#define NCH 128         // T_/TCH

__device__ __forceinline__ unsigned short f2bf(float f) {
  unsigned int u = __float_as_uint(f);
  u += 0x7fffu + ((u >> 16) & 1u);   // RNE
  return (unsigned short)(u >> 16);
}
__device__ __forceinline__ float sigm(float v) { return 1.f / (1.f + __expf(-v)); }
__device__ __forceinline__ float tanh_f(float v) { return 2.f / (1.f + __expf(-2.f * v)) - 1.f; }

__device__ __forceinline__ void gl16(const ushort_t* g, ushort_t* l) {
  __builtin_amdgcn_global_load_lds(
      (const __attribute__((address_space(1))) unsigned int*)g,
      (__attribute__((address_space(3))) unsigned int*)l, 16, 0, 0);
}

// ---------------- P1: transpose+convert x [B][C][T] f32 -> xp [B][T+1][C] bf16 ----------
__global__ __launch_bounds__(256) void qrnn_p1(const float* __restrict__ x,
                                               ushort_t* __restrict__ xp) {
  __shared__ float tile[32][129];
  const int tid = threadIdx.x;
  const int b = blockIdx.z, c0 = blockIdx.y * 32, t0 = blockIdx.x * 128;
#pragma unroll
  for (int p = 0; p < 4; ++p) {
    const int j = tid + p * 256;        // 0..1023 float4 chunks
    const int c = j >> 5, q = j & 31;
    float4 v = *reinterpret_cast<const float4*>(x + ((size_t)(b * C_ + c0 + c)) * T_ + t0 + q * 4);
    tile[c][q * 4 + 0] = v.x; tile[c][q * 4 + 1] = v.y;
    tile[c][q * 4 + 2] = v.z; tile[c][q * 4 + 3] = v.w;
  }
  __syncthreads();
  const int t = tid >> 1, ch = (tid & 1) * 16;
  ushort_t o[16];
#pragma unroll
  for (int i = 0; i < 16; ++i) o[i] = f2bf(tile[ch + i][t]);
  ushort_t* dst = xp + ((size_t)b * (T_ + 1) + 1 + t0 + t) * C_ + c0 + ch;
  *reinterpret_cast<uint4*>(dst) = *reinterpret_cast<uint4*>(&o[0]);
  *reinterpret_cast<uint4*>(dst + 8) = *reinterpret_cast<uint4*>(&o[8]);
}

// ---------------- P2: Wcat[g][h][k'] bf16; k'<256 -> W[h][k'][1] (x_t), else W[h][k'-256][0]
__global__ __launch_bounds__(256) void qrnn_p2(const float* __restrict__ Wz,
                                               const float* __restrict__ Wf,
                                               const float* __restrict__ Wo,
                                               ushort_t* __restrict__ wc,
                                               ushort_t* __restrict__ xp) {
  const int idx = blockIdx.x * 256 + threadIdx.x;    // < 3*256*512
  if (blockIdx.x == 0) {                             // zero pad rows (t = -1)
#pragma unroll
    for (int b = 0; b < B_; ++b) xp[((size_t)b * (T_ + 1)) * C_ + threadIdx.x] = 0;
  }
  const int g = idx >> 17;
  const int rem = idx & 131071;
  const int h = rem >> 9;
  const int kp = rem & 511;
  const int c = kp & 255;
  const int tap = (kp < 256) ? 1 : 0;
  const float* W = (g == 0) ? Wz : ((g == 1) ? Wf : Wo);
  wc[idx] = f2bf(W[((size_t)h * C_ + c) * 2 + tap]);
}

// ---------------- G: bf16 MFMA GEMM [768 x 512] x [512 x T] per batch + bias + act ------
// Depth-2 prefetch, counted vmcnt(4) (never 0 in steady state), raw s_barrier, setprio.
// Per K-step: ds_read cur; lgkmcnt(0); BAR1 (cur free); gl16 -> cur (ks+2); MFMA;
//             vmcnt(4) (ks+1 staged); BAR2.
__global__ __launch_bounds__(256) void qrnn_gates(const ushort_t* __restrict__ xp,
                                                  const ushort_t* __restrict__ wc,
                                                  const float* __restrict__ bz,
                                                  const float* __restrict__ bfv,
                                                  const float* __restrict__ bo,
                                                  float* __restrict__ zfo) {
  __shared__ ushort_t As[2][128 * 32];   // 8KB each buf
  __shared__ ushort_t Bs[2][128 * 32];
  const int tid = threadIdx.x;
  const int lane = tid & 63;
  const int wid = tid >> 6;
  const int wm = wid >> 1, wn = wid & 1;
  const int l15 = lane & 15, g4 = lane >> 4;
  const int b = blockIdx.z;
  const int m0 = blockIdx.y * 128;   // row in stacked [z|f|o]
  const int t0 = blockIdx.x * 128;

  // staging: 512 chunks of 16B per tile; chunk j -> row=j>>2, slot=j&3; source slot XOR'd
  const int j0 = wid * 128 + lane;
  const int j1 = j0 + 64;
  const int r0 = j0 >> 2, s0 = (j0 & 3) ^ ((r0 >> 1) & 3);
  const int r1 = j1 >> 2, s1 = (j1 & 3) ^ ((r1 >> 1) & 3);
  const ushort_t* asrc0 = wc + (size_t)(m0 + r0) * 512 + s0 * 8;
  const ushort_t* asrc1 = wc + (size_t)(m0 + r1) * 512 + s1 * 8;
  const ushort_t* bsrc0 = xp + ((size_t)b * (T_ + 1) + t0 + r0) * C_ + s0 * 8;
  const ushort_t* bsrc1 = xp + ((size_t)b * (T_ + 1) + t0 + r1) * C_ + s1 * 8;
  const int dA0 = (wid * 128) * 8;       // wave-uniform dest element offsets
  const int dA1 = (wid * 128 + 64) * 8;

  f32x4 acc[4][4];
#pragma unroll
  for (int i = 0; i < 4; ++i)
#pragma unroll
    for (int j = 0; j < 4; ++j) acc[i][j] = (f32x4){0.f, 0.f, 0.f, 0.f};

  const int swz = (l15 >> 1) & 3;
  const int aslot = (g4 ^ swz) * 8;

  // prologue: stage ks=0 into buf0, ks=1 into buf1; wait for buf0 only.
  gl16(asrc0, &As[0][dA0]);
  gl16(asrc1, &As[0][dA1]);
  gl16(bsrc0 + C_, &Bs[0][dA0]);
  gl16(bsrc1 + C_, &Bs[0][dA1]);
  gl16(asrc0 + 32, &As[1][dA0]);
  gl16(asrc1 + 32, &As[1][dA1]);
  gl16(bsrc0 + C_ + 32, &Bs[1][dA0]);
  gl16(bsrc1 + C_ + 32, &Bs[1][dA1]);
  asm volatile("s_waitcnt vmcnt(4)" ::: "memory");
  __builtin_amdgcn_sched_barrier(0);
  __builtin_amdgcn_s_barrier();
  __builtin_amdgcn_sched_barrier(0);

#pragma unroll
  for (int ks = 0; ks < 16; ++ks) {
    const int cur = ks & 1;
    short8_t a[4], bb[4];
#pragma unroll
    for (int mi = 0; mi < 4; ++mi) {
      const int row = wm * 64 + mi * 16 + l15;
      a[mi] = *reinterpret_cast<const short8_t*>(&As[cur][row * 32 + aslot]);
    }
#pragma unroll
    for (int ni = 0; ni < 4; ++ni) {
      const int row = wn * 64 + ni * 16 + l15;
      bb[ni] = *reinterpret_cast<const short8_t*>(&Bs[cur][row * 32 + aslot]);
    }
    asm volatile("s_waitcnt lgkmcnt(0)" ::: "memory");
    __builtin_amdgcn_sched_barrier(0);
    __builtin_amdgcn_s_barrier();      // BAR1: all waves' reads of buf[cur] complete
    __builtin_amdgcn_sched_barrier(0);
    if (ks < 14) {                     // stage ks+2 into buf[cur] (now free)
      const int nk = ks + 2;
      const int ak = nk * 32;
      const int bk = (nk >= 8) ? (ak - 256) : (C_ + ak);
      gl16(asrc0 + ak, &As[cur][dA0]);
      gl16(asrc1 + ak, &As[cur][dA1]);
      gl16(bsrc0 + bk, &Bs[cur][dA0]);
      gl16(bsrc1 + bk, &Bs[cur][dA1]);
    }
    __builtin_amdgcn_s_setprio(1);
#pragma unroll
    for (int mi = 0; mi < 4; ++mi)
#pragma unroll
      for (int ni = 0; ni < 4; ++ni)
        acc[mi][ni] = __builtin_amdgcn_mfma_f32_16x16x32_bf16(a[mi], bb[ni], acc[mi][ni], 0, 0, 0);
    __builtin_amdgcn_s_setprio(0);
    if (ks < 14)
      asm volatile("s_waitcnt vmcnt(4)" ::: "memory");   // ks+1's loads done; ours in flight
    else
      asm volatile("s_waitcnt vmcnt(0)" ::: "memory");   // tail drain
    __builtin_amdgcn_sched_barrier(0);
    __builtin_amdgcn_s_barrier();      // BAR2: buf[ks+1] staged for all waves
    __builtin_amdgcn_sched_barrier(0);
  }

  // epilogue: bias + activation, store fp32 to zfo[gate][b][h][t]
  const int gate = m0 >> 8;
  const float* bias = (gate == 0) ? bz : ((gate == 1) ? bfv : bo);
  const int hb = (m0 & 255) + wm * 64;
  float* obase = zfo + ((size_t)(gate * B_ + b)) * H_ * T_;
#pragma unroll
  for (int mi = 0; mi < 4; ++mi) {
#pragma unroll
    for (int r4 = 0; r4 < 4; ++r4) {
      const int h = hb + mi * 16 + g4 * 4 + r4;   // C/D map: row=(lane>>4)*4+reg
      const float bvv = bias[h];
      float* rowp = obase + (size_t)h * T_ + t0 + wn * 64 + l15;  // col=lane&15
#pragma unroll
      for (int ni = 0; ni < 4; ++ni) {
        float v = acc[mi][ni][r4] + bvv;
        v = (gate == 0) ? tanh_f(v) : sigm(v);
        rowp[ni * 16] = v;
      }
    }
  }
}

// ---------------- S1: per-chunk aggregates only (P = cumprod f, C = local end value) ----
__global__ __launch_bounds__(256) void qrnn_s1(const float* __restrict__ zfo,
                                               float* __restrict__ aggP,
                                               float* __restrict__ aggC) {
  __shared__ float lf[256][33];
  __shared__ float lz[256][33];
  const int tid = threadIdx.x;
  const int chunk = blockIdx.x;
  const int b = blockIdx.y;
  const int t0 = chunk * TCH;
  const float* zbase = zfo + (size_t)b * H_ * T_;
  const float* fbase = zfo + (size_t)(B_ + b) * H_ * T_;
  const int lr = tid >> 3, lc = (tid & 7) * 4;
#pragma unroll
  for (int pass = 0; pass < 8; ++pass) {
    const int row = pass * 32 + lr;
    float4 fv = *reinterpret_cast<const float4*>(fbase + (size_t)row * T_ + t0 + lc);
    float4 zv = *reinterpret_cast<const float4*>(zbase + (size_t)row * T_ + t0 + lc);
    lf[row][lc] = fv.x; lf[row][lc + 1] = fv.y; lf[row][lc + 2] = fv.z; lf[row][lc + 3] = fv.w;
    lz[row][lc] = zv.x; lz[row][lc + 1] = zv.y; lz[row][lc + 2] = zv.z; lz[row][lc + 3] = zv.w;
  }
  __syncthreads();
  float c = 0.f, p = 1.f;
#pragma unroll
  for (int t = 0; t < TCH; ++t) {
    const float f = lf[tid][t], z = lz[tid][t];
    c = f * (c - z) + z;   // = f*c + (1-f)*z
    p *= f;
  }
  aggP[((size_t)b * NCH + chunk) * H_ + tid] = p;
  aggC[((size_t)b * NCH + chunk) * H_ + tid] = c;
}

// ---------------- S2: scan over chunk aggregates -> carry_in -----------------------------
__global__ __launch_bounds__(256) void qrnn_s2(const float* __restrict__ aggP,
                                               const float* __restrict__ aggC,
                                               float* __restrict__ cin) {
  const int b = blockIdx.x, h = threadIdx.x;
  float carry = 0.f;
  for (int jb = 0; jb < NCH; jb += 8) {
    float P[8], Cv[8];
#pragma unroll
    for (int u = 0; u < 8; ++u) {
      P[u] = aggP[((size_t)b * NCH + jb + u) * H_ + h];
      Cv[u] = aggC[((size_t)b * NCH + jb + u) * H_ + h];
    }
#pragma unroll
    for (int u = 0; u < 8; ++u) {
      cin[((size_t)b * NCH + jb + u) * H_ + h] = carry;
      carry = Cv[u] + P[u] * carry;
    }
  }
}

// ---------------- S3: local re-scan with carry folded; write c and h = o*c --------------
__global__ __launch_bounds__(256) void qrnn_s3(const float* __restrict__ zfo,
                                               const float* __restrict__ cin,
                                               float* __restrict__ outc,
                                               float* __restrict__ outh) {
  __shared__ float lz[128][33];
  __shared__ float lf[128][33];
  __shared__ float lo[128][33];
  const int tid = threadIdx.x;
  const int chunk = blockIdx.x;          // 0..127
  const int h0 = blockIdx.y * 128;       // 0 or 128
  const int b = blockIdx.z;
  const int t0 = chunk * TCH;
  const float* zb = zfo + (size_t)b * H_ * T_;
  const float* fb = zfo + (size_t)(B_ + b) * H_ * T_;
  const float* ob = zfo + (size_t)(2 * B_ + b) * H_ * T_;
#pragma unroll
  for (int i = 0; i < 4; ++i) {
    const int j = tid + i * 256;         // 0..1023
    const int row = j >> 3, c4 = (j & 7) * 4;
    const size_t goff = (size_t)(h0 + row) * T_ + t0 + c4;
    float4 zv = *reinterpret_cast<const float4*>(zb + goff);
    float4 fv = *reinterpret_cast<const float4*>(fb + goff);
    float4 ov = *reinterpret_cast<const float4*>(ob + goff);
    lz[row][c4] = zv.x; lz[row][c4 + 1] = zv.y; lz[row][c4 + 2] = zv.z; lz[row][c4 + 3] = zv.w;
    lf[row][c4] = fv.x; lf[row][c4 + 1] = fv.y; lf[row][c4 + 2] = fv.z; lf[row][c4 + 3] = fv.w;
    lo[row][c4] = ov.x; lo[row][c4 + 1] = ov.y; lo[row][c4 + 2] = ov.z; lo[row][c4 + 3] = ov.w;
  }
  __syncthreads();
  if (tid < 128) {
    float c = cin[((size_t)b * NCH + chunk) * H_ + h0 + tid];
#pragma unroll
    for (int t = 0; t < TCH; ++t) {
      const float f = lf[tid][t], z = lz[tid][t];
      c = f * (c - z) + z;
      lz[tid][t] = c;                 // c
      lf[tid][t] = lo[tid][t] * c;    // h = o*c (f slot reused)
    }
  }
  __syncthreads();
  float* cb = outc + (size_t)b * H_ * T_;
  float* hb = outh + (size_t)b * H_ * T_;
#pragma unroll
  for (int i = 0; i < 4; ++i) {
    const int j = tid + i * 256;
    const int row = j >> 3, c4 = (j & 7) * 4;
    const size_t goff = (size_t)(h0 + row) * T_ + t0 + c4;
    float4 cv = make_float4(lz[row][c4], lz[row][c4 + 1], lz[row][c4 + 2], lz[row][c4 + 3]);
    float4 hv = make_float4(lf[row][c4], lf[row][c4 + 1], lf[row][c4 + 2], lf[row][c4 + 3]);
    *reinterpret_cast<float4*>(cb + goff) = cv;
    *reinterpret_cast<float4*>(hb + goff) = hv;
  }
}

extern "C" void kernel_launch(void* const* d_in, const int* in_sizes, int n_in,
                              void* d_out, int out_size, void* d_ws, size_t ws_size,
                              hipStream_t stream) {
  const float* x  = (const float*)d_in[0];
  const float* Wz = (const float*)d_in[1];
  const float* bz = (const float*)d_in[2];
  const float* Wf = (const float*)d_in[3];
  const float* bfv= (const float*)d_in[4];
  const float* Wo = (const float*)d_in[5];
  const float* bo = (const float*)d_in[6];
  // Wi/bi (d_in[7], d_in[8]) are dead in the reference.

  float* outh = (float*)d_out;                        // [B][H][T]
  float* outc = outh + (size_t)B_ * H_ * T_;          // [B][H][T]

  // workspace layout (bytes)
  constexpr size_t XP_OFF  = 0;                       // B*(T+1)*C*2 = 16,781,312
  constexpr size_t WC_OFF  = 16781312;                //    786,432
  constexpr size_t ZFO_OFF = 17567744;                // 100,663,296
  constexpr size_t AGP_OFF = 118231040;               //  1,048,576
  constexpr size_t AGC_OFF = 119279616;               //  1,048,576
  constexpr size_t CIN_OFF = 120328192;               //  1,048,576
  constexpr size_t WS_NEED = 121376768;
  if (ws_size < WS_NEED) return;

  ushort_t* xp  = (ushort_t*)((char*)d_ws + XP_OFF);
  ushort_t* wcp = (ushort_t*)((char*)d_ws + WC_OFF);
  float* zfo  = (float*)((char*)d_ws + ZFO_OFF);
  float* aggP = (float*)((char*)d_ws + AGP_OFF);
  float* aggC = (float*)((char*)d_ws + AGC_OFF);
  float* cin  = (float*)((char*)d_ws + CIN_OFF);

  qrnn_p1<<<dim3(T_ / 128, C_ / 32, B_), 256, 0, stream>>>(x, xp);
  qrnn_p2<<<dim3((3 * H_ * 512) / 256), 256, 0, stream>>>(Wz, Wf, Wo, wcp, xp);
  qrnn_gates<<<dim3(T_ / 128, 6, B_), 256, 0, stream>>>(xp, wcp, bz, bfv, bo, zfo);
  qrnn_s1<<<dim3(NCH, B_), 256, 0, stream>>>(zfo, aggP, aggC);
  qrnn_s2<<<dim3(B_), 256, 0, stream>>>(aggP, aggC, cin);
  qrnn_s3<<<dim3(NCH, 2, B_), 256, 0, stream>>>(zfo, cin, outc, outh);
}